// Round 4
// baseline (391.725 us; speedup 1.0000x reference)
//
#include <hip/hip_runtime.h>

// Batched Kalman filter: B batches, N=8 state, M=4 meas, fp32.
// R7 = R6 pipeline skeleton, re-balanced for concurrency:
//  - Stage only F,P via global_load_lds (32KB/group vs R6's 48KB) ->
//    5 single-wave blocks/CU (was 3). grid 768 -> 1280.
//  - Q: direct per-lane loads of the 12 lower-triangle float4 chunks;
//    latency hidden under the ~800-FMA F P F^T phase (compiler inserts
//    its own counted vmcnt before first use; gl_lds stay in flight).
//  - H,R,z,x: direct per-lane loads as in R6.
//  - Pipeline choreography unchanged: ds_read F,P -> lgkmcnt(0) (WAR) ->
//    issue next group's 32 gl_lds -> compute -> 26 stores ->
//    s_waitcnt vmcnt(26) (post-staging vmem = exactly the 26 stores).
//  - waves_per_eu(2): VGPR cap 256 guarantees 2 waves/SIMD schedulable
//    (R6 measured 180 VGPR with near-identical code).
// Outputs flat: x_new[B*8], P_new[B*64], K[B*32].

#define EPS 1e-6f
#define SYMIDX(r, c) ((r) * ((r) + 1) / 2 + (c))

__device__ __forceinline__ void gl_lds16(const float* g, float* l) {
    __builtin_amdgcn_global_load_lds(
        (const __attribute__((address_space(1))) void*)(uintptr_t)g,
        (__attribute__((address_space(3))) void*)(unsigned)(uintptr_t)l,
        16, 0, 0);
}

// Stage 64 batches x 64 floats into linear LDS via global_load_lds.
// LDS slot (b, e') holds global chunk e' ^ (b&7) of batch b: issue i covers
// slots i*64+lane with b = i*4 + lane/16, e' = lane&15. Global side: each
// issue reads a permutation of 4 full 256B batch rows -> 1KB coalesced.
__device__ __forceinline__ void stage64(const float* __restrict__ src, int gstart,
                                        float* ldsbase, int lane, int B) {
#pragma unroll
    for (int i = 0; i < 16; ++i) {
        int b = i * 4 + (lane >> 4);
        int e = lane & 15;
        int gb = gstart + b;
        if (gb > B - 1) gb = B - 1;
        gl_lds16(src + (size_t)gb * 64 + (size_t)((e ^ (b & 7)) * 4),
                 ldsbase + i * 256);
    }
}

__global__ __launch_bounds__(64) __attribute__((amdgpu_waves_per_eu(2)))
void kf_kernel(const float* __restrict__ x_est,
               const float* __restrict__ P_est,
               const float* __restrict__ Fin,
               const float* __restrict__ Qin,
               const float* __restrict__ zin,
               const float* __restrict__ Hin,
               const float* __restrict__ Rin,
               float* __restrict__ out, int B) {
    const int lane = threadIdx.x;
    const int ngroups = (B + 63) >> 6;
    int g = blockIdx.x;
    if (g >= ngroups) return;
    const int stride = gridDim.x;

    // F: floats [0,4096)  P: [4096,8192)  = 32 KB -> 5 blocks/CU
    __shared__ __align__(16) float lds[8192];

    // ---- prologue: stage group g, full drain ----
    stage64(Fin, g * 64, lds, lane, B);
    stage64(P_est, g * 64, lds + 4096, lane, B);
    asm volatile("s_waitcnt vmcnt(0)" ::: "memory");

    while (true) {
        const int b0 = g * 64 + lane;
        const bool full = (g * 64 + 64 <= B);
        const int sw = lane & 7;
        const float4* L4 = reinterpret_cast<const float4*>(lds);
        const int gn = g + stride;
        const int gnc = (gn < ngroups) ? gn : 0;  // clamped prefetch target

        // ---- LDS -> registers (swizzled, conflict-free ds_read_b128) ----
        float Fr[64];
#pragma unroll
        for (int r = 0; r < 8; ++r) {
            float4 a = L4[lane * 16 + ((2 * r) ^ sw)];
            float4 c = L4[lane * 16 + ((2 * r + 1) ^ sw)];
            Fr[r * 8 + 0] = a.x; Fr[r * 8 + 1] = a.y; Fr[r * 8 + 2] = a.z; Fr[r * 8 + 3] = a.w;
            Fr[r * 8 + 4] = c.x; Fr[r * 8 + 5] = c.y; Fr[r * 8 + 6] = c.z; Fr[r * 8 + 7] = c.w;
        }
        float Ps[36];
#pragma unroll
        for (int r = 0; r < 8; ++r) {
            float4 a = L4[1024 + lane * 16 + ((2 * r) ^ sw)];
            float rw[4] = {a.x, a.y, a.z, a.w};
            if (r < 4) {
#pragma unroll
                for (int j = 0; j < 4; ++j)
                    if (j <= r) Ps[SYMIDX(r, j)] = rw[j];
            } else {
                float4 c = L4[1024 + lane * 16 + ((2 * r + 1) ^ sw)];
                float rw2[4] = {c.x, c.y, c.z, c.w};
#pragma unroll
                for (int j = 0; j < 4; ++j) Ps[SYMIDX(r, j)] = rw[j];
#pragma unroll
                for (int j = 4; j < 8; ++j)
                    if (j <= r) Ps[SYMIDX(r, j)] = rw2[j - 4];
            }
        }
        // WAR: all LDS reads complete before next group's gl_lds can land.
        asm volatile("s_waitcnt lgkmcnt(0)" ::: "memory");

        // ---- direct loads for CURRENT group (before the staging block) ----
        int b0c = (b0 > B - 1) ? B - 1 : b0;
        // Q: lower-triangle chunks only (rows 0-3: chunk 2r; rows 4-7: both)
        float Qs[36];
        {
            const float4* Q4 = reinterpret_cast<const float4*>(Qin + (size_t)b0c * 64);
            float4 q0 = Q4[0], q2 = Q4[2], q4 = Q4[4], q6 = Q4[6];
            float4 q8 = Q4[8], q9 = Q4[9], q10 = Q4[10], q11 = Q4[11];
            float4 q12 = Q4[12], q13 = Q4[13], q14 = Q4[14], q15 = Q4[15];
            Qs[SYMIDX(0,0)] = q0.x;
            Qs[SYMIDX(1,0)] = q2.x;  Qs[SYMIDX(1,1)] = q2.y;
            Qs[SYMIDX(2,0)] = q4.x;  Qs[SYMIDX(2,1)] = q4.y;  Qs[SYMIDX(2,2)] = q4.z;
            Qs[SYMIDX(3,0)] = q6.x;  Qs[SYMIDX(3,1)] = q6.y;  Qs[SYMIDX(3,2)] = q6.z;  Qs[SYMIDX(3,3)] = q6.w;
            Qs[SYMIDX(4,0)] = q8.x;  Qs[SYMIDX(4,1)] = q8.y;  Qs[SYMIDX(4,2)] = q8.z;  Qs[SYMIDX(4,3)] = q8.w;
            Qs[SYMIDX(4,4)] = q9.x;
            Qs[SYMIDX(5,0)] = q10.x; Qs[SYMIDX(5,1)] = q10.y; Qs[SYMIDX(5,2)] = q10.z; Qs[SYMIDX(5,3)] = q10.w;
            Qs[SYMIDX(5,4)] = q11.x; Qs[SYMIDX(5,5)] = q11.y;
            Qs[SYMIDX(6,0)] = q12.x; Qs[SYMIDX(6,1)] = q12.y; Qs[SYMIDX(6,2)] = q12.z; Qs[SYMIDX(6,3)] = q12.w;
            Qs[SYMIDX(6,4)] = q13.x; Qs[SYMIDX(6,5)] = q13.y; Qs[SYMIDX(6,6)] = q13.z;
            Qs[SYMIDX(7,0)] = q14.x; Qs[SYMIDX(7,1)] = q14.y; Qs[SYMIDX(7,2)] = q14.z; Qs[SYMIDX(7,3)] = q14.w;
            Qs[SYMIDX(7,4)] = q15.x; Qs[SYMIDX(7,5)] = q15.y; Qs[SYMIDX(7,6)] = q15.z; Qs[SYMIDX(7,7)] = q15.w;
        }
        float Hm[32];
        {
            const float4* H4 = reinterpret_cast<const float4*>(Hin + (size_t)b0c * 32);
#pragma unroll
            for (int i = 0; i < 8; ++i) {
                float4 h = H4[i];
                Hm[4 * i + 0] = h.x; Hm[4 * i + 1] = h.y; Hm[4 * i + 2] = h.z; Hm[4 * i + 3] = h.w;
            }
        }
        const float4* Rp = reinterpret_cast<const float4*>(Rin + (size_t)b0c * 16);
        float4 r0 = Rp[0], r1 = Rp[1], r2 = Rp[2], r3 = Rp[3];
        float4 zz = reinterpret_cast<const float4*>(zin)[b0c];
        float4 xa = reinterpret_cast<const float4*>(x_est)[2 * b0c];
        float4 xb = reinterpret_cast<const float4*>(x_est)[2 * b0c + 1];

        // Pin: direct loads issue before the staging block.
        asm volatile("" ::: "memory");

        // ---- issue next group's staging (32 gl_lds, stay in flight) ----
        stage64(Fin, gnc * 64, lds, lane, B);
        stage64(P_est, gnc * 64, lds + 4096, lane, B);
        // Compile barrier: after here the ONLY vmem ops are the 26 stores.
        asm volatile("" ::: "memory");

        // ---- x_pred = F x ----
        float xp[8];
        {
            float x[8] = {xa.x, xa.y, xa.z, xa.w, xb.x, xb.y, xb.z, xb.w};
#pragma unroll
            for (int i = 0; i < 8; ++i) {
                float s = 0.f;
#pragma unroll
                for (int j = 0; j < 8; ++j) s += Fr[i * 8 + j] * x[j];
                xp[i] = s;
            }
        }

        // ---- Pp(sym) = F P F^T + Q ----
        float Pps[36];
#pragma unroll
        for (int i = 0; i < 8; ++i) {
            float Ti[8];
#pragma unroll
            for (int j = 0; j < 8; ++j) {
                float s = 0.f;
#pragma unroll
                for (int k = 0; k < 8; ++k) {
                    float pkj = (k >= j) ? Ps[SYMIDX(k, j)] : Ps[SYMIDX(j, k)];
                    s += Fr[i * 8 + k] * pkj;
                }
                Ti[j] = s;
            }
#pragma unroll
            for (int j = 0; j <= i; ++j) {
                float s = Qs[SYMIDX(i, j)];
#pragma unroll
                for (int k = 0; k < 8; ++k) s += Ti[k] * Fr[j * 8 + k];
                Pps[SYMIDX(i, j)] = s;
            }
        }
        // Fr, Ps, Qs dead.

        // ---- HP = H * Pp ----
        float HP[32];
#pragma unroll
        for (int i = 0; i < 4; ++i)
#pragma unroll
            for (int j = 0; j < 8; ++j) {
                float s = 0.f;
#pragma unroll
                for (int k = 0; k < 8; ++k) {
                    float pkj = (k >= j) ? Pps[SYMIDX(k, j)] : Pps[SYMIDX(j, k)];
                    s += Hm[i * 8 + k] * pkj;
                }
                HP[i * 8 + j] = s;
            }

        // ---- y = z - H x_pred ----
        float y[4];
        {
            float zv[4] = {zz.x, zz.y, zz.z, zz.w};
#pragma unroll
            for (int i = 0; i < 4; ++i) {
                float s = zv[i];
#pragma unroll
                for (int k = 0; k < 8; ++k) s -= Hm[i * 8 + k] * xp[k];
                y[i] = s;
            }
        }

        // ---- S = HP H^T + R + eps I ----
        float S[16];
        {
            float Rr[16] = {r0.x, r0.y, r0.z, r0.w, r1.x, r1.y, r1.z, r1.w,
                            r2.x, r2.y, r2.z, r2.w, r3.x, r3.y, r3.z, r3.w};
#pragma unroll
            for (int i = 0; i < 4; ++i)
#pragma unroll
                for (int j = 0; j < 4; ++j) {
                    float s = Rr[i * 4 + j];
#pragma unroll
                    for (int k = 0; k < 8; ++k) s += HP[i * 8 + k] * Hm[j * 8 + k];
                    if (i == j) s += EPS;
                    S[i * 4 + j] = s;
                }
        }

        // ---- Sinv via adjugate ----
        float inv[16];
        inv[0]  =  S[5]*S[10]*S[15] - S[5]*S[11]*S[14] - S[9]*S[6]*S[15] + S[9]*S[7]*S[14] + S[13]*S[6]*S[11] - S[13]*S[7]*S[10];
        inv[4]  = -S[4]*S[10]*S[15] + S[4]*S[11]*S[14] + S[8]*S[6]*S[15] - S[8]*S[7]*S[14] - S[12]*S[6]*S[11] + S[12]*S[7]*S[10];
        inv[8]  =  S[4]*S[9]*S[15]  - S[4]*S[11]*S[13] - S[8]*S[5]*S[15] + S[8]*S[7]*S[13] + S[12]*S[5]*S[11] - S[12]*S[7]*S[9];
        inv[12] = -S[4]*S[9]*S[14]  + S[4]*S[10]*S[13] + S[8]*S[5]*S[14] - S[8]*S[6]*S[13] - S[12]*S[5]*S[10] + S[12]*S[6]*S[9];
        inv[1]  = -S[1]*S[10]*S[15] + S[1]*S[11]*S[14] + S[9]*S[2]*S[15] - S[9]*S[3]*S[14] - S[13]*S[2]*S[11] + S[13]*S[3]*S[10];
        inv[5]  =  S[0]*S[10]*S[15] - S[0]*S[11]*S[14] - S[8]*S[2]*S[15] + S[8]*S[3]*S[14] + S[12]*S[2]*S[11] - S[12]*S[3]*S[10];
        inv[9]  = -S[0]*S[9]*S[15]  + S[0]*S[11]*S[13] + S[8]*S[1]*S[15] - S[8]*S[3]*S[13] - S[12]*S[1]*S[11] + S[12]*S[3]*S[9];
        inv[13] =  S[0]*S[9]*S[14]  - S[0]*S[10]*S[13] - S[8]*S[1]*S[14] + S[8]*S[2]*S[13] + S[12]*S[1]*S[10] - S[12]*S[2]*S[9];
        inv[2]  =  S[1]*S[6]*S[15]  - S[1]*S[7]*S[14]  - S[5]*S[2]*S[15] + S[5]*S[3]*S[14] + S[13]*S[2]*S[7]  - S[13]*S[3]*S[6];
        inv[6]  = -S[0]*S[6]*S[15]  + S[0]*S[7]*S[14]  + S[4]*S[2]*S[15] - S[4]*S[3]*S[14] - S[12]*S[2]*S[7]  + S[12]*S[3]*S[6];
        inv[10] =  S[0]*S[5]*S[15]  - S[0]*S[7]*S[13]  - S[4]*S[1]*S[15] + S[4]*S[3]*S[13] + S[12]*S[1]*S[7]  - S[12]*S[3]*S[5];
        inv[14] = -S[0]*S[5]*S[14]  + S[0]*S[6]*S[13]  + S[4]*S[1]*S[14] - S[4]*S[2]*S[13] - S[12]*S[1]*S[6]  + S[12]*S[2]*S[5];
        inv[3]  = -S[1]*S[6]*S[11]  + S[1]*S[7]*S[10]  + S[5]*S[2]*S[11] - S[5]*S[3]*S[10] - S[9]*S[2]*S[7]   + S[9]*S[3]*S[6];
        inv[7]  =  S[0]*S[6]*S[11]  - S[0]*S[7]*S[10]  - S[4]*S[2]*S[11] + S[4]*S[3]*S[10] + S[8]*S[2]*S[7]   - S[8]*S[3]*S[6];
        inv[11] = -S[0]*S[5]*S[11]  + S[0]*S[7]*S[9]   + S[4]*S[1]*S[11] - S[4]*S[3]*S[9]  - S[8]*S[1]*S[7]   + S[8]*S[3]*S[5];
        inv[15] =  S[0]*S[5]*S[10]  - S[0]*S[6]*S[9]   - S[4]*S[1]*S[10] + S[4]*S[2]*S[9]  + S[8]*S[1]*S[6]   - S[8]*S[2]*S[5];
        float det = S[0]*inv[0] + S[1]*inv[4] + S[2]*inv[8] + S[3]*inv[12];
        float rdet = 1.0f / det;
#pragma unroll
        for (int i = 0; i < 16; ++i) inv[i] *= rdet;

        // ---- K = (HP)^T * Sinv (Pp symmetric) ----
        float K[32];
#pragma unroll
        for (int i = 0; i < 8; ++i)
#pragma unroll
            for (int j = 0; j < 4; ++j) {
                float s = 0.f;
#pragma unroll
                for (int k = 0; k < 4; ++k) s += HP[k * 8 + i] * inv[k * 4 + j];
                K[i * 4 + j] = s;
            }

        // ---- outputs: exactly 26 float4 cached stores ----
        auto doStores = [&]() {
            float4* xo = reinterpret_cast<float4*>(out + (size_t)b0 * 8);
            float xn[8];
#pragma unroll
            for (int i = 0; i < 8; ++i) {
                float s = xp[i];
#pragma unroll
                for (int k = 0; k < 4; ++k) s += K[i * 4 + k] * y[k];
                xn[i] = s;
            }
            xo[0] = make_float4(xn[0], xn[1], xn[2], xn[3]);
            xo[1] = make_float4(xn[4], xn[5], xn[6], xn[7]);

            float4* po = reinterpret_cast<float4*>(out + (size_t)B * 8 + (size_t)b0 * 64);
#pragma unroll
            for (int i = 0; i < 8; ++i) {
                float r[8];
#pragma unroll
                for (int j = 0; j < 8; ++j) {
                    float pij = (i >= j) ? Pps[SYMIDX(i, j)] : Pps[SYMIDX(j, i)];
                    float s = pij;
#pragma unroll
                    for (int k = 0; k < 4; ++k) s -= K[i * 4 + k] * HP[k * 8 + j];
                    r[j] = s;
                }
                po[2 * i + 0] = make_float4(r[0], r[1], r[2], r[3]);
                po[2 * i + 1] = make_float4(r[4], r[5], r[6], r[7]);
            }

            float4* ko = reinterpret_cast<float4*>(out + (size_t)B * 72 + (size_t)b0 * 32);
#pragma unroll
            for (int i = 0; i < 8; ++i)
                ko[i] = make_float4(K[4 * i + 0], K[4 * i + 1], K[4 * i + 2], K[4 * i + 3]);
        };

        // ---- counted wait: post-staging vmem = 26 stores exactly, so
        // vmcnt(26) forces everything older (27 direct loads + 32 gl_lds)
        // complete while all 26 stores may remain in flight. ----
        if (full) {
            doStores();
            asm volatile("s_waitcnt vmcnt(26)" ::: "memory");
        } else {
            if (b0 < B) doStores();
            asm volatile("s_waitcnt vmcnt(0)" ::: "memory");
        }

        if (gn >= ngroups) break;
        g = gn;
    }
}

extern "C" void kernel_launch(void* const* d_in, const int* in_sizes, int n_in,
                              void* d_out, int out_size, void* d_ws, size_t ws_size,
                              hipStream_t stream) {
    const float* x_est = (const float*)d_in[0];
    const float* P_est = (const float*)d_in[1];
    const float* F     = (const float*)d_in[2];
    const float* Q     = (const float*)d_in[3];
    const float* z     = (const float*)d_in[4];
    const float* H     = (const float*)d_in[5];
    const float* R     = (const float*)d_in[6];
    float* out = (float*)d_out;
    int B = in_sizes[0] / 8;
    int ngroups = (B + 63) / 64;
    // 32KB LDS -> 5 blocks/CU; 1280 = 5 * 256 CUs.
    int grid = ngroups < 1280 ? ngroups : 1280;
    kf_kernel<<<grid, 64, 0, stream>>>(x_est, P_est, F, Q, z, H, R, out, B);
}

// Round 5
// 335.742 us; speedup vs baseline: 1.1667x; 1.1667x over previous
//
#include <hip/hip_runtime.h>

// Batched Kalman filter: B batches, N=8 state, M=4 meas, fp32.
// R8 = R7 structure with the register-allocator attribute fixed.
//  - R7's amdgpu_waves_per_eu(2) set only MIN waves/EU -> allocator kept
//    its default 4-waves/EU target (128 VGPR) and spilled ~200 live floats
//    to scratch: VGPR 180->128, FETCH +85MB, WRITE +45MB, occupancy capped
//    by scratch backing, 127->230us. (Same failure mode as R2's history.)
//  - Fix: waves_per_eu(1,2): min=1 -> no forced spill (cap 512); max=2 ->
//    allocator won't squeeze below 256 VGPR chasing occupancy (LDS caps us
//    at 5 single-wave blocks/CU anyway).
//  - Structure unchanged from R7: stage F,P via global_load_lds (32KB ->
//    5 blocks/CU); Q (lower-triangle chunks), H, R, z, x direct per-lane
//    loads issued BEFORE the staging block; post-staging vmem = exactly
//    the 26 float4 stores -> steady-state s_waitcnt vmcnt(26).
// Outputs flat: x_new[B*8], P_new[B*64], K[B*32].

#define EPS 1e-6f
#define SYMIDX(r, c) ((r) * ((r) + 1) / 2 + (c))

__device__ __forceinline__ void gl_lds16(const float* g, float* l) {
    __builtin_amdgcn_global_load_lds(
        (const __attribute__((address_space(1))) void*)(uintptr_t)g,
        (__attribute__((address_space(3))) void*)(unsigned)(uintptr_t)l,
        16, 0, 0);
}

// Stage 64 batches x 64 floats into linear LDS via global_load_lds.
// LDS slot (b, e') holds global chunk e' ^ (b&7) of batch b: issue i covers
// slots i*64+lane with b = i*4 + lane/16, e' = lane&15. Global side: each
// issue reads a permutation of 4 full 256B batch rows -> 1KB coalesced.
__device__ __forceinline__ void stage64(const float* __restrict__ src, int gstart,
                                        float* ldsbase, int lane, int B) {
#pragma unroll
    for (int i = 0; i < 16; ++i) {
        int b = i * 4 + (lane >> 4);
        int e = lane & 15;
        int gb = gstart + b;
        if (gb > B - 1) gb = B - 1;
        gl_lds16(src + (size_t)gb * 64 + (size_t)((e ^ (b & 7)) * 4),
                 ldsbase + i * 256);
    }
}

__global__ __launch_bounds__(64) __attribute__((amdgpu_waves_per_eu(1, 2)))
void kf_kernel(const float* __restrict__ x_est,
               const float* __restrict__ P_est,
               const float* __restrict__ Fin,
               const float* __restrict__ Qin,
               const float* __restrict__ zin,
               const float* __restrict__ Hin,
               const float* __restrict__ Rin,
               float* __restrict__ out, int B) {
    const int lane = threadIdx.x;
    const int ngroups = (B + 63) >> 6;
    int g = blockIdx.x;
    if (g >= ngroups) return;
    const int stride = gridDim.x;

    // F: floats [0,4096)  P: [4096,8192)  = 32 KB -> 5 blocks/CU
    __shared__ __align__(16) float lds[8192];

    // ---- prologue: stage group g, full drain ----
    stage64(Fin, g * 64, lds, lane, B);
    stage64(P_est, g * 64, lds + 4096, lane, B);
    asm volatile("s_waitcnt vmcnt(0)" ::: "memory");

    while (true) {
        const int b0 = g * 64 + lane;
        const bool full = (g * 64 + 64 <= B);
        const int sw = lane & 7;
        const float4* L4 = reinterpret_cast<const float4*>(lds);
        const int gn = g + stride;
        const int gnc = (gn < ngroups) ? gn : 0;  // clamped prefetch target

        // ---- LDS -> registers (swizzled, conflict-free ds_read_b128) ----
        float Fr[64];
#pragma unroll
        for (int r = 0; r < 8; ++r) {
            float4 a = L4[lane * 16 + ((2 * r) ^ sw)];
            float4 c = L4[lane * 16 + ((2 * r + 1) ^ sw)];
            Fr[r * 8 + 0] = a.x; Fr[r * 8 + 1] = a.y; Fr[r * 8 + 2] = a.z; Fr[r * 8 + 3] = a.w;
            Fr[r * 8 + 4] = c.x; Fr[r * 8 + 5] = c.y; Fr[r * 8 + 6] = c.z; Fr[r * 8 + 7] = c.w;
        }
        float Ps[36];
#pragma unroll
        for (int r = 0; r < 8; ++r) {
            float4 a = L4[1024 + lane * 16 + ((2 * r) ^ sw)];
            float rw[4] = {a.x, a.y, a.z, a.w};
            if (r < 4) {
#pragma unroll
                for (int j = 0; j < 4; ++j)
                    if (j <= r) Ps[SYMIDX(r, j)] = rw[j];
            } else {
                float4 c = L4[1024 + lane * 16 + ((2 * r + 1) ^ sw)];
                float rw2[4] = {c.x, c.y, c.z, c.w};
#pragma unroll
                for (int j = 0; j < 4; ++j) Ps[SYMIDX(r, j)] = rw[j];
#pragma unroll
                for (int j = 4; j < 8; ++j)
                    if (j <= r) Ps[SYMIDX(r, j)] = rw2[j - 4];
            }
        }
        // WAR: all LDS reads complete before next group's gl_lds can land.
        asm volatile("s_waitcnt lgkmcnt(0)" ::: "memory");

        // ---- direct loads for CURRENT group (before the staging block) ----
        int b0c = (b0 > B - 1) ? B - 1 : b0;
        // Q: lower-triangle chunks only (rows 0-3: chunk 2r; rows 4-7: both)
        float Qs[36];
        {
            const float4* Q4 = reinterpret_cast<const float4*>(Qin + (size_t)b0c * 64);
            float4 q0 = Q4[0], q2 = Q4[2], q4 = Q4[4], q6 = Q4[6];
            float4 q8 = Q4[8], q9 = Q4[9], q10 = Q4[10], q11 = Q4[11];
            float4 q12 = Q4[12], q13 = Q4[13], q14 = Q4[14], q15 = Q4[15];
            Qs[SYMIDX(0,0)] = q0.x;
            Qs[SYMIDX(1,0)] = q2.x;  Qs[SYMIDX(1,1)] = q2.y;
            Qs[SYMIDX(2,0)] = q4.x;  Qs[SYMIDX(2,1)] = q4.y;  Qs[SYMIDX(2,2)] = q4.z;
            Qs[SYMIDX(3,0)] = q6.x;  Qs[SYMIDX(3,1)] = q6.y;  Qs[SYMIDX(3,2)] = q6.z;  Qs[SYMIDX(3,3)] = q6.w;
            Qs[SYMIDX(4,0)] = q8.x;  Qs[SYMIDX(4,1)] = q8.y;  Qs[SYMIDX(4,2)] = q8.z;  Qs[SYMIDX(4,3)] = q8.w;
            Qs[SYMIDX(4,4)] = q9.x;
            Qs[SYMIDX(5,0)] = q10.x; Qs[SYMIDX(5,1)] = q10.y; Qs[SYMIDX(5,2)] = q10.z; Qs[SYMIDX(5,3)] = q10.w;
            Qs[SYMIDX(5,4)] = q11.x; Qs[SYMIDX(5,5)] = q11.y;
            Qs[SYMIDX(6,0)] = q12.x; Qs[SYMIDX(6,1)] = q12.y; Qs[SYMIDX(6,2)] = q12.z; Qs[SYMIDX(6,3)] = q12.w;
            Qs[SYMIDX(6,4)] = q13.x; Qs[SYMIDX(6,5)] = q13.y; Qs[SYMIDX(6,6)] = q13.z;
            Qs[SYMIDX(7,0)] = q14.x; Qs[SYMIDX(7,1)] = q14.y; Qs[SYMIDX(7,2)] = q14.z; Qs[SYMIDX(7,3)] = q14.w;
            Qs[SYMIDX(7,4)] = q15.x; Qs[SYMIDX(7,5)] = q15.y; Qs[SYMIDX(7,6)] = q15.z; Qs[SYMIDX(7,7)] = q15.w;
        }
        float Hm[32];
        {
            const float4* H4 = reinterpret_cast<const float4*>(Hin + (size_t)b0c * 32);
#pragma unroll
            for (int i = 0; i < 8; ++i) {
                float4 h = H4[i];
                Hm[4 * i + 0] = h.x; Hm[4 * i + 1] = h.y; Hm[4 * i + 2] = h.z; Hm[4 * i + 3] = h.w;
            }
        }
        const float4* Rp = reinterpret_cast<const float4*>(Rin + (size_t)b0c * 16);
        float4 r0 = Rp[0], r1 = Rp[1], r2 = Rp[2], r3 = Rp[3];
        float4 zz = reinterpret_cast<const float4*>(zin)[b0c];
        float4 xa = reinterpret_cast<const float4*>(x_est)[2 * b0c];
        float4 xb = reinterpret_cast<const float4*>(x_est)[2 * b0c + 1];

        // Pin: direct loads issue before the staging block.
        asm volatile("" ::: "memory");

        // ---- issue next group's staging (32 gl_lds, stay in flight) ----
        stage64(Fin, gnc * 64, lds, lane, B);
        stage64(P_est, gnc * 64, lds + 4096, lane, B);
        // Compile barrier: after here the ONLY vmem ops are the 26 stores.
        asm volatile("" ::: "memory");

        // ---- x_pred = F x ----
        float xp[8];
        {
            float x[8] = {xa.x, xa.y, xa.z, xa.w, xb.x, xb.y, xb.z, xb.w};
#pragma unroll
            for (int i = 0; i < 8; ++i) {
                float s = 0.f;
#pragma unroll
                for (int j = 0; j < 8; ++j) s += Fr[i * 8 + j] * x[j];
                xp[i] = s;
            }
        }

        // ---- Pp(sym) = F P F^T + Q ----
        float Pps[36];
#pragma unroll
        for (int i = 0; i < 8; ++i) {
            float Ti[8];
#pragma unroll
            for (int j = 0; j < 8; ++j) {
                float s = 0.f;
#pragma unroll
                for (int k = 0; k < 8; ++k) {
                    float pkj = (k >= j) ? Ps[SYMIDX(k, j)] : Ps[SYMIDX(j, k)];
                    s += Fr[i * 8 + k] * pkj;
                }
                Ti[j] = s;
            }
#pragma unroll
            for (int j = 0; j <= i; ++j) {
                float s = Qs[SYMIDX(i, j)];
#pragma unroll
                for (int k = 0; k < 8; ++k) s += Ti[k] * Fr[j * 8 + k];
                Pps[SYMIDX(i, j)] = s;
            }
        }
        // Fr, Ps, Qs dead.

        // ---- HP = H * Pp ----
        float HP[32];
#pragma unroll
        for (int i = 0; i < 4; ++i)
#pragma unroll
            for (int j = 0; j < 8; ++j) {
                float s = 0.f;
#pragma unroll
                for (int k = 0; k < 8; ++k) {
                    float pkj = (k >= j) ? Pps[SYMIDX(k, j)] : Pps[SYMIDX(j, k)];
                    s += Hm[i * 8 + k] * pkj;
                }
                HP[i * 8 + j] = s;
            }

        // ---- y = z - H x_pred ----
        float y[4];
        {
            float zv[4] = {zz.x, zz.y, zz.z, zz.w};
#pragma unroll
            for (int i = 0; i < 4; ++i) {
                float s = zv[i];
#pragma unroll
                for (int k = 0; k < 8; ++k) s -= Hm[i * 8 + k] * xp[k];
                y[i] = s;
            }
        }

        // ---- S = HP H^T + R + eps I ----
        float S[16];
        {
            float Rr[16] = {r0.x, r0.y, r0.z, r0.w, r1.x, r1.y, r1.z, r1.w,
                            r2.x, r2.y, r2.z, r2.w, r3.x, r3.y, r3.z, r3.w};
#pragma unroll
            for (int i = 0; i < 4; ++i)
#pragma unroll
                for (int j = 0; j < 4; ++j) {
                    float s = Rr[i * 4 + j];
#pragma unroll
                    for (int k = 0; k < 8; ++k) s += HP[i * 8 + k] * Hm[j * 8 + k];
                    if (i == j) s += EPS;
                    S[i * 4 + j] = s;
                }
        }

        // ---- Sinv via adjugate ----
        float inv[16];
        inv[0]  =  S[5]*S[10]*S[15] - S[5]*S[11]*S[14] - S[9]*S[6]*S[15] + S[9]*S[7]*S[14] + S[13]*S[6]*S[11] - S[13]*S[7]*S[10];
        inv[4]  = -S[4]*S[10]*S[15] + S[4]*S[11]*S[14] + S[8]*S[6]*S[15] - S[8]*S[7]*S[14] - S[12]*S[6]*S[11] + S[12]*S[7]*S[10];
        inv[8]  =  S[4]*S[9]*S[15]  - S[4]*S[11]*S[13] - S[8]*S[5]*S[15] + S[8]*S[7]*S[13] + S[12]*S[5]*S[11] - S[12]*S[7]*S[9];
        inv[12] = -S[4]*S[9]*S[14]  + S[4]*S[10]*S[13] + S[8]*S[5]*S[14] - S[8]*S[6]*S[13] - S[12]*S[5]*S[10] + S[12]*S[6]*S[9];
        inv[1]  = -S[1]*S[10]*S[15] + S[1]*S[11]*S[14] + S[9]*S[2]*S[15] - S[9]*S[3]*S[14] - S[13]*S[2]*S[11] + S[13]*S[3]*S[10];
        inv[5]  =  S[0]*S[10]*S[15] - S[0]*S[11]*S[14] - S[8]*S[2]*S[15] + S[8]*S[3]*S[14] + S[12]*S[2]*S[11] - S[12]*S[3]*S[10];
        inv[9]  = -S[0]*S[9]*S[15]  + S[0]*S[11]*S[13] + S[8]*S[1]*S[15] - S[8]*S[3]*S[13] - S[12]*S[1]*S[11] + S[12]*S[3]*S[9];
        inv[13] =  S[0]*S[9]*S[14]  - S[0]*S[10]*S[13] - S[8]*S[1]*S[14] + S[8]*S[2]*S[13] + S[12]*S[1]*S[10] - S[12]*S[2]*S[9];
        inv[2]  =  S[1]*S[6]*S[15]  - S[1]*S[7]*S[14]  - S[5]*S[2]*S[15] + S[5]*S[3]*S[14] + S[13]*S[2]*S[7]  - S[13]*S[3]*S[6];
        inv[6]  = -S[0]*S[6]*S[15]  + S[0]*S[7]*S[14]  + S[4]*S[2]*S[15] - S[4]*S[3]*S[14] - S[12]*S[2]*S[7]  + S[12]*S[3]*S[6];
        inv[10] =  S[0]*S[5]*S[15]  - S[0]*S[7]*S[13]  - S[4]*S[1]*S[15] + S[4]*S[3]*S[13] + S[12]*S[1]*S[7]  - S[12]*S[3]*S[5];
        inv[14] = -S[0]*S[5]*S[14]  + S[0]*S[6]*S[13]  + S[4]*S[1]*S[14] - S[4]*S[2]*S[13] - S[12]*S[1]*S[6]  + S[12]*S[2]*S[5];
        inv[3]  = -S[1]*S[6]*S[11]  + S[1]*S[7]*S[10]  + S[5]*S[2]*S[11] - S[5]*S[3]*S[10] - S[9]*S[2]*S[7]   + S[9]*S[3]*S[6];
        inv[7]  =  S[0]*S[6]*S[11]  - S[0]*S[7]*S[10]  - S[4]*S[2]*S[11] + S[4]*S[3]*S[10] + S[8]*S[2]*S[7]   - S[8]*S[3]*S[6];
        inv[11] = -S[0]*S[5]*S[11]  + S[0]*S[7]*S[9]   + S[4]*S[1]*S[11] - S[4]*S[3]*S[9]  - S[8]*S[1]*S[7]   + S[8]*S[3]*S[5];
        inv[15] =  S[0]*S[5]*S[10]  - S[0]*S[6]*S[9]   - S[4]*S[1]*S[10] + S[4]*S[2]*S[9]  + S[8]*S[1]*S[6]   - S[8]*S[2]*S[5];
        float det = S[0]*inv[0] + S[1]*inv[4] + S[2]*inv[8] + S[3]*inv[12];
        float rdet = 1.0f / det;
#pragma unroll
        for (int i = 0; i < 16; ++i) inv[i] *= rdet;

        // ---- K = (HP)^T * Sinv (Pp symmetric) ----
        float K[32];
#pragma unroll
        for (int i = 0; i < 8; ++i)
#pragma unroll
            for (int j = 0; j < 4; ++j) {
                float s = 0.f;
#pragma unroll
                for (int k = 0; k < 4; ++k) s += HP[k * 8 + i] * inv[k * 4 + j];
                K[i * 4 + j] = s;
            }

        // ---- outputs: exactly 26 float4 cached stores ----
        auto doStores = [&]() {
            float4* xo = reinterpret_cast<float4*>(out + (size_t)b0 * 8);
            float xn[8];
#pragma unroll
            for (int i = 0; i < 8; ++i) {
                float s = xp[i];
#pragma unroll
                for (int k = 0; k < 4; ++k) s += K[i * 4 + k] * y[k];
                xn[i] = s;
            }
            xo[0] = make_float4(xn[0], xn[1], xn[2], xn[3]);
            xo[1] = make_float4(xn[4], xn[5], xn[6], xn[7]);

            float4* po = reinterpret_cast<float4*>(out + (size_t)B * 8 + (size_t)b0 * 64);
#pragma unroll
            for (int i = 0; i < 8; ++i) {
                float r[8];
#pragma unroll
                for (int j = 0; j < 8; ++j) {
                    float pij = (i >= j) ? Pps[SYMIDX(i, j)] : Pps[SYMIDX(j, i)];
                    float s = pij;
#pragma unroll
                    for (int k = 0; k < 4; ++k) s -= K[i * 4 + k] * HP[k * 8 + j];
                    r[j] = s;
                }
                po[2 * i + 0] = make_float4(r[0], r[1], r[2], r[3]);
                po[2 * i + 1] = make_float4(r[4], r[5], r[6], r[7]);
            }

            float4* ko = reinterpret_cast<float4*>(out + (size_t)B * 72 + (size_t)b0 * 32);
#pragma unroll
            for (int i = 0; i < 8; ++i)
                ko[i] = make_float4(K[4 * i + 0], K[4 * i + 1], K[4 * i + 2], K[4 * i + 3]);
        };

        // ---- counted wait: post-staging vmem = 26 stores exactly, so
        // vmcnt(26) forces everything older (27 direct loads + 32 gl_lds)
        // complete while all 26 stores may remain in flight. ----
        if (full) {
            doStores();
            asm volatile("s_waitcnt vmcnt(26)" ::: "memory");
        } else {
            if (b0 < B) doStores();
            asm volatile("s_waitcnt vmcnt(0)" ::: "memory");
        }

        if (gn >= ngroups) break;
        g = gn;
    }
}

extern "C" void kernel_launch(void* const* d_in, const int* in_sizes, int n_in,
                              void* d_out, int out_size, void* d_ws, size_t ws_size,
                              hipStream_t stream) {
    const float* x_est = (const float*)d_in[0];
    const float* P_est = (const float*)d_in[1];
    const float* F     = (const float*)d_in[2];
    const float* Q     = (const float*)d_in[3];
    const float* z     = (const float*)d_in[4];
    const float* H     = (const float*)d_in[5];
    const float* R     = (const float*)d_in[6];
    float* out = (float*)d_out;
    int B = in_sizes[0] / 8;
    int ngroups = (B + 63) / 64;
    // 32KB LDS -> 5 blocks/CU; 1280 = 5 * 256 CUs.
    int grid = ngroups < 1280 ? ngroups : 1280;
    kf_kernel<<<grid, 64, 0, stream>>>(x_est, P_est, F, Q, z, H, R, out, B);
}